// Round 4
// baseline (594.882 us; speedup 1.0000x reference)
//
#include <hip/hip_runtime.h>

// ES gradient for 2-layer MLP (D_IN=1024, HID=2048, D_OUT=10, POP=40, STD=0.1).
// k_base (fp32) -> k_xsplit (x -> f16 hi/lo) -> k_big (split-f16 MFMA, j64 x b256
// tiles, B-frags direct from global, E staged via LDS once) -> k_loss -> k_rank
// -> k_grad.  Losses only matter through RANKS (gaps ~1e-2); split-f16 GEMM err
// ~1e-5, pp-f16 err ~6e-4 => rank-exact.

#define NPLL 2119690LL          // N_PARAMS
#define S1_  2097152            // W1 end
#define S2_  2099200            // b1 end
#define S3_  2119680            // W2 end

// ws layout (f32 units):
//   base : [0, 524288)            base[j][b]  (x@W1+b1)
//   pp   : [524288, 3801088)      f16 [40][2][32][256][10]  (13.1 MB)
//   loss : [3801088, 3801168)
//   g    : [3801168, 3801208)
//   xh   : [3801216, +131072)     f16 [256][1024]
//   xl   : [3932288, +131072)     f16 [256][1024]
#define WS_PP   524288
#define WS_LOSS 3801088
#define WS_G    3801168
#define WS_XH   3801216
#define WS_XL   3932288

typedef _Float16 f16;
typedef __fp16   fp16x2 __attribute__((ext_vector_type(2)));
typedef _Float16 f16x8 __attribute__((ext_vector_type(8)));
typedef float    f32x4 __attribute__((ext_vector_type(4)));

__device__ __forceinline__ unsigned pk2r(float a, float b, float& ra, float& rb) {
  fp16x2 h = __builtin_amdgcn_cvt_pkrtz(a, b);   // v_cvt_pkrtz_f16_f32
  ra = a - (float)h[0];
  rb = b - (float)h[1];
  return __builtin_bit_cast(unsigned, h);
}
__device__ __forceinline__ unsigned pk2(float a, float b) {
  fp16x2 h = __builtin_amdgcn_cvt_pkrtz(a, b);
  return __builtin_bit_cast(unsigned, h);
}
__device__ __forceinline__ unsigned packh(float a, float b) {  // RTN pack
  union { f16 h[2]; unsigned u; } v;
  v.h[0] = (f16)a; v.h[1] = (f16)b;
  return v.u;
}

// ---------------- k_base: base[j][b] = (x @ W1)[b][j] + b1[j] (fp32) --------
__global__ __launch_bounds__(256) void k_base(const float* __restrict__ x,
                                              const float* __restrict__ W1,
                                              const float* __restrict__ b1,
                                              float* __restrict__ base) {
  constexpr int STR = 72;
  __shared__ float xs[32 * STR];
  __shared__ float es[32 * STR];
  const int t  = threadIdx.x;
  const int j0 = blockIdx.x * 64;
  const int b0 = blockIdx.y * 32;
  const int tj = t & 15;
  const int tb = t >> 4;
  float acc[4][2] = {};
  for (int k0 = 0; k0 < 1024; k0 += 32) {
    __syncthreads();
    {
      int bb = t >> 3, kq = t & 7;
      float4 v = *(const float4*)&x[(size_t)(b0 + bb) * 1024 + k0 + kq * 4];
      int kb = kq * 4;
      xs[(kb + 0) * STR + bb] = v.x;
      xs[(kb + 1) * STR + bb] = v.y;
      xs[(kb + 2) * STR + bb] = v.z;
      xs[(kb + 3) * STR + bb] = v.w;
    }
#pragma unroll
    for (int r = 0; r < 2; ++r) {
      int idx = t + r * 256;
      int k = idx >> 4, jq = idx & 15, col = jq * 4;
      float4 v = *(const float4*)&W1[(size_t)(k0 + k) * 2048 + j0 + col];
      *(float4*)&es[k * STR + col + 4 * (col >> 5)] = v;
    }
    __syncthreads();
#pragma unroll 8
    for (int k = 0; k < 32; ++k) {
      const int ce = tj * 4;
      float4 e = *(const float4*)&es[k * STR + ce + 4 * (ce >> 5)];
      float2 a = *(const float2*)&xs[k * STR + tb * 2];
      acc[0][0] += e.x * a.x; acc[0][1] += e.x * a.y;
      acc[1][0] += e.y * a.x; acc[1][1] += e.y * a.y;
      acc[2][0] += e.z * a.x; acc[2][1] += e.z * a.y;
      acc[3][0] += e.w * a.x; acc[3][1] += e.w * a.y;
    }
  }
#pragma unroll
  for (int jj = 0; jj < 4; ++jj) {
    int j = j0 + tj * 4 + jj;
    float bv = b1[j];
    float2 o = make_float2(acc[jj][0] + bv, acc[jj][1] + bv);
    *(float2*)&base[(size_t)j * 256 + b0 + tb * 2] = o;
  }
}

// ---------------- k_xsplit: x (f32) -> xh + xl (f16 hi/lo) ------------------
__global__ __launch_bounds__(256) void k_xsplit(const float* __restrict__ x,
                                                f16* __restrict__ xh,
                                                f16* __restrict__ xl) {
  const int i = (blockIdx.x * 256 + threadIdx.x) * 8;  // 128 blocks: 262144 total
  float4 a = *(const float4*)&x[i];
  float4 b = *(const float4*)&x[i + 4];
  float v[8] = {a.x, a.y, a.z, a.w, b.x, b.y, b.z, b.w};
  float r[8];
  uint4 H, L;
  H.x = pk2r(v[0], v[1], r[0], r[1]);
  H.y = pk2r(v[2], v[3], r[2], r[3]);
  H.z = pk2r(v[4], v[5], r[4], r[5]);
  H.w = pk2r(v[6], v[7], r[6], r[7]);
  L.x = pk2(r[0], r[1]); L.y = pk2(r[2], r[3]);
  L.z = pk2(r[4], r[5]); L.w = pk2(r[6], r[7]);
  *(uint4*)&xh[i] = H;
  *(uint4*)&xl[i] = L;
}

// ---------------- k_big: split-f16 MFMA, tile j64 x b256 --------------------
// grid (32 = jt, 40 = p); 256 threads = 4 waves; wave = b-slice of 64.
#define ESTR 72   // f16 per LDS row: cols 0..31 hi(k), 32..63 lo(k), 8 pad
__global__ __launch_bounds__(256, 2) void k_big(const f16* __restrict__ xh,
                                                const f16* __restrict__ xl,
                                                const float* __restrict__ noise,
                                                const float* __restrict__ W2,
                                                const float* __restrict__ base,
                                                unsigned* __restrict__ ppu) {
  __shared__ __align__(16) f16 eA[64 * ESTR];  // E^T tile [j][k-cols]
  __shared__ float w2l[640], e2l[640], e1l[64];

  const int t    = threadIdx.x;
  const int jt   = blockIdx.x, p = blockIdx.y;
  const int j0   = jt * 64;
  const int wave = t >> 6, lane = t & 63;
  const int lm   = lane & 15, g8 = (lane >> 4) * 8, g4 = (lane >> 4) * 4;
  const int wb   = wave;            // wave's 64-wide b-slice
  const size_t pN = (size_t)p * NPLL;
  const int rl = lane;              // staging j-row
  const int kq = wave * 8;          // staging k-offset within 32-k step

  for (int i = t; i < 640; i += 256) {
    w2l[i] = W2[j0 * 10 + i];
    e2l[i] = noise[pN + S2_ + (size_t)j0 * 10 + i];
  }
  if (t < 64) e1l[t] = noise[pN + S1_ + j0 + t];

  float ve[8];
  f32x4 acc[4][4];
#pragma unroll
  for (int a = 0; a < 4; ++a)
#pragma unroll
    for (int b = 0; b < 4; ++b) acc[a][b] = (f32x4){0.f, 0.f, 0.f, 0.f};

#define LOADE(K0)                                                              \
  do {                                                                         \
    const float* eg = &noise[pN + (size_t)((K0) + kq) * 2048 + j0 + rl];       \
    _Pragma("unroll") for (int d = 0; d < 8; ++d) ve[d] = eg[(size_t)d * 2048];\
  } while (0)

  LOADE(0);
  for (int ks = 0; ks < 32; ++ks) {
    const int k0 = ks * 32;
    __syncthreads();   // previous MFMA reads done; eA free
    {  // convert E regs -> LDS hi/lo
      float r0, r1, r2, r3, r4, r5, r6, r7;
      uint4 H, L;
      H.x = pk2r(ve[0], ve[1], r0, r1);
      H.y = pk2r(ve[2], ve[3], r2, r3);
      H.z = pk2r(ve[4], ve[5], r4, r5);
      H.w = pk2r(ve[6], ve[7], r6, r7);
      *(uint4*)&eA[rl * ESTR + kq] = H;
      L.x = pk2(r0, r1); L.y = pk2(r2, r3);
      L.z = pk2(r4, r5); L.w = pk2(r6, r7);
      *(uint4*)&eA[rl * ESTR + 32 + kq] = L;
    }
    // B fragments for THIS k-step from global f16 (L2-resident; issued before
    // next E prefetch so B's waitcnt doesn't drain the E stream)
    f16x8 Bh[4], Bl[4];
#pragma unroll
    for (int nf = 0; nf < 4; ++nf) {
      const size_t bo = (size_t)(wb * 64 + nf * 16 + lm) * 1024 + k0 + g8;
      Bh[nf] = *(const f16x8*)&xh[bo];
      Bl[nf] = *(const f16x8*)&xl[bo];
    }
    if (ks < 31) LOADE((ks + 1) * 32);   // prefetch next E into regs
    __syncthreads();   // eA tile ready
    f16x8 Ah[4], Al[4];
#pragma unroll
    for (int mf = 0; mf < 4; ++mf) {
      Ah[mf] = *(const f16x8*)&eA[(mf * 16 + lm) * ESTR + g8];
      Al[mf] = *(const f16x8*)&eA[(mf * 16 + lm) * ESTR + 32 + g8];
    }
#pragma unroll
    for (int mf = 0; mf < 4; ++mf)
#pragma unroll
      for (int nf = 0; nf < 4; ++nf) {
        acc[mf][nf] = __builtin_amdgcn_mfma_f32_16x16x32_f16(Ah[mf], Bh[nf], acc[mf][nf], 0, 0, 0);
        acc[mf][nf] = __builtin_amdgcn_mfma_f32_16x16x32_f16(Ah[mf], Bl[nf], acc[mf][nf], 0, 0, 0);
        acc[mf][nf] = __builtin_amdgcn_mfma_f32_16x16x32_f16(Al[mf], Bh[nf], acc[mf][nf], 0, 0, 0);
      }
  }

  // ---- epilogue: one sign at a time (caps VGPR) ----
#pragma unroll 1
  for (int s = 0; s < 2; ++s) {
    const float sf = s ? -0.1f : 0.1f;
    float ppv[4][10];
#pragma unroll
    for (int nf = 0; nf < 4; ++nf)
#pragma unroll
      for (int o = 0; o < 10; ++o) ppv[nf][o] = 0.f;
#pragma unroll
    for (int mf = 0; mf < 4; ++mf)
#pragma unroll
      for (int r = 0; r < 4; ++r) {
        const int jl = mf * 16 + g4 + r;     // D row = (lane>>4)*4 + reg
        const float e1v = e1l[jl];
        float w2s[10];
#pragma unroll
        for (int o = 0; o < 10; ++o)
          w2s[o] = fmaf(sf, e2l[jl * 10 + o], w2l[jl * 10 + o]);
#pragma unroll
        for (int nf = 0; nf < 4; ++nf) {
          const int bl = wb * 64 + nf * 16 + lm;   // D col = lane&15
          const float bs = base[(size_t)(j0 + jl) * 256 + bl];
          const float h = fmaxf(fmaf(sf, acc[mf][nf][r] + e1v, bs), 0.f);
#pragma unroll
          for (int o = 0; o < 10; ++o) ppv[nf][o] = fmaf(h, w2s[o], ppv[nf][o]);
        }
      }
    // reduce over the 4 row-groups (lane bits 4,5); lanes 0..15 hold b-columns
#pragma unroll
    for (int nf = 0; nf < 4; ++nf)
#pragma unroll
      for (int o = 0; o < 10; ++o) {
        float v = ppv[nf][o];
        v += __shfl_xor(v, 16, 64);
        v += __shfl_xor(v, 32, 64);
        ppv[nf][o] = v;
      }
    if (lane < 16) {
#pragma unroll
      for (int nf = 0; nf < 4; ++nf) {
        const int bl = wb * 64 + nf * 16 + lm;
        const size_t u0 = ((((size_t)p * 2 + s) * 32 + jt) * 256 + bl) * 5;
        ppu[u0 + 0] = packh(ppv[nf][0], ppv[nf][1]);
        ppu[u0 + 1] = packh(ppv[nf][2], ppv[nf][3]);
        ppu[u0 + 2] = packh(ppv[nf][4], ppv[nf][5]);
        ppu[u0 + 3] = packh(ppv[nf][6], ppv[nf][7]);
        ppu[u0 + 4] = packh(ppv[nf][8], ppv[nf][9]);
      }
    }
  }
#undef LOADE
}

// ---------------- k_loss: 80 losses ----------------
__global__ __launch_bounds__(256) void k_loss(const unsigned* __restrict__ ppu,
                                              const float* __restrict__ y,
                                              const float* __restrict__ b2,
                                              const float* __restrict__ noise,
                                              float* __restrict__ loss) {
  const int b = threadIdx.x;
  const int p = blockIdx.x >> 1, s = blockIdx.x & 1;
  const float sf = s ? -0.1f : 0.1f;
  const size_t pN = (size_t)p * NPLL;
  float pred[10];
#pragma unroll
  for (int o = 0; o < 10; ++o) pred[o] = b2[o] + sf * noise[pN + S3_ + o];
  for (int jt = 0; jt < 32; ++jt) {
    const size_t u0 = ((((size_t)p * 2 + s) * 32 + jt) * 256 + b) * 5;
#pragma unroll
    for (int q = 0; q < 5; ++q) {
      union { unsigned u; f16 h[2]; } w;
      w.u = ppu[u0 + q];
      pred[2 * q]     += (float)w.h[0];
      pred[2 * q + 1] += (float)w.h[1];
    }
  }
  float e = 0.f;
#pragma unroll
  for (int o = 0; o < 10; ++o) {
    float d = pred[o] - y[b * 10 + o];
    e += d * d;
  }
  __shared__ float red[256];
  red[b] = e;
  __syncthreads();
  for (int st = 128; st > 0; st >>= 1) {
    if (b < st) red[b] += red[b + st];
    __syncthreads();
  }
  if (b == 0) loss[blockIdx.x] = red[0] * (1.0f / 2560.0f);
}

// ---------------- k_rank: stable centered ranks -> pair coefficients --------
__global__ void k_rank(const float* __restrict__ loss, float* __restrict__ g) {
  __shared__ float ls[80];
  __shared__ float rk[80];
  const int t = threadIdx.x;
  if (t < 80) ls[t] = loss[t];
  __syncthreads();
  if (t < 80) {
    float li = ls[t];
    int r = 0;
    for (int j = 0; j < 80; ++j) {
      float lj = ls[j];
      r += (lj < li) || (lj == li && j < t);  // stable tie-break = argsort
    }
    rk[t] = (float)r;
  }
  __syncthreads();
  if (t < 40) g[t] = (rk[2 * t] - rk[2 * t + 1]) * (1.0f / (79.0f * 40.0f));
}

// ---------------- k_grad: out[k] = sum_p noise[p][k] * g[p] -----------------
__global__ __launch_bounds__(256) void k_grad(const float* __restrict__ noise,
                                              const float* __restrict__ g,
                                              float* __restrict__ out) {
  __shared__ float gg[40];
  const int t = threadIdx.x;
  if (t < 40) gg[t] = g[t];
  __syncthreads();
  const long long NH = NPLL / 2;
  long long idx = (long long)blockIdx.x * 256 + t;
  if (idx >= NH) return;
  float2 a = make_float2(0.f, 0.f);
#pragma unroll 8
  for (int p = 0; p < 40; ++p) {
    float2 v = *(const float2*)&noise[(size_t)p * NPLL + idx * 2];
    a.x += v.x * gg[p];
    a.y += v.y * gg[p];
  }
  *(float2*)&out[idx * 2] = a;
}

extern "C" void kernel_launch(void* const* d_in, const int* in_sizes, int n_in,
                              void* d_out, int out_size, void* d_ws, size_t ws_size,
                              hipStream_t stream) {
  const float* x     = (const float*)d_in[0];
  const float* y     = (const float*)d_in[1];
  const float* W1    = (const float*)d_in[2];
  const float* b1    = (const float*)d_in[3];
  const float* W2    = (const float*)d_in[4];
  const float* b2    = (const float*)d_in[5];
  const float* noise = (const float*)d_in[6];
  float* out  = (float*)d_out;
  float* ws   = (float*)d_ws;   // ~16.3 MB used
  float* base = ws;
  unsigned* ppu = (unsigned*)(ws + WS_PP);
  float* loss = ws + WS_LOSS;
  float* g    = ws + WS_G;
  f16* xh = (f16*)(ws + WS_XH);
  f16* xl = (f16*)(ws + WS_XL);

  k_base<<<dim3(32, 8), 256, 0, stream>>>(x, W1, b1, base);
  k_xsplit<<<128, 256, 0, stream>>>(x, xh, xl);
  k_big<<<dim3(32, 40), 256, 0, stream>>>(xh, xl, noise, W2, base, ppu);
  k_loss<<<80, 256, 0, stream>>>(ppu, y, b2, noise, loss);
  k_rank<<<1, 128, 0, stream>>>(loss, g);
  k_grad<<<4141, 256, 0, stream>>>(noise, g, out);
}